// Round 14
// baseline (187.596 us; speedup 1.0000x reference)
//
#include <hip/hip_runtime.h>
#include <hip/hip_bf16.h>

#define B_SZ 4
#define T_SEQ 1024
#define DM 128
#define ED_ 256
#define NS 64
#define LOG2E 1.44269504088896340736f

// workspace layout (float elements). Total = 6,389,760 floats = 25.6 MB (accepted size).
// dxpT is TRANSPOSED [b][e][t] x {delta, delta*xs}; yrT is TRANSPOSED [b][e][t].
// WTi (in_proj transposed) lives in the YR head: k0 -> k2, dead before k5 writes YR.
// WoT (out_proj transposed) lives in the XSR head: written by k5's extra blocks, read by k6.
#define OFF_Z      0u         /* 524288  f32  z (residual, read by K6)            */
#define OFF_ZG     524288u    /* 1048576 f32  gate (k2 -> k6)                     */
#define OFF_XSR    1572864u   /* 1048576 f32  conv input (k2 -> k4b); head=WoT    */
#define OFF_WC     2621440u   /* 98304   f32  WcT[k][c] transposed combined wt    */
#define OFF_YR     2719744u   /* 1048576 f32  scan out [b][e][t]; head hosts WTi  */
#define OFF_DPX    3768320u   /* 2097152 f32  {delta, delta*xs} [b][e][t] pairs   */
#define OFF_BC     5865472u   /* 524288  f32  {B, C} [b][t][n] pairs (k4b -> k5)  */

__device__ __forceinline__ float sigmoidf_(float x){ return 1.f/(1.f+__expf(-x)); }
__device__ __forceinline__ float exp2_(float x){ return __builtin_amdgcn_exp2f(x); }
__device__ __forceinline__ float rlane_(float v, int l){
  return __int_as_float(__builtin_amdgcn_readlane(__float_as_int(v), l));
}

// Fused DPP add: p += dpp(p) in ONE instruction. bound_ctrl:0 => invalid lanes read 0.
#define DPPR(p, ctl) asm("v_add_f32_dpp %0, %0, %0 " ctl " row_mask:0xf bank_mask:0xf bound_ctrl:0" : "+v"(p))
#define DPP6(p) do{ DPPR(p,"row_shr:1"); DPPR(p,"row_shr:2"); DPPR(p,"row_shr:4"); \
                    DPPR(p,"row_shr:8"); DPPR(p,"row_bcast:15"); DPPR(p,"row_bcast:31"); }while(0)

// K0: transpose in_proj W (512x128 row-major) -> WTi[k][c] (128x512).
__global__ __launch_bounds__(256) void k0_t(const float* W, float* WTi){
  int k = blockIdx.x;        // 0..127
  int c = threadIdx.x;       // 0..255
  WTi[k*512 + c]       = W[(size_t)c*128 + k];
  WTi[k*512 + c + 256] = W[(size_t)(c+256)*128 + k];
}

// K2f: blocks 0..511: fused [z = zseq+aux@auxW.T+auxb ; zn=RMSNorm(z)*rms_w] -> LDS,
//      then xz = zn @ in_proj_W.T -> xsr | zg, reading WTi[k][c] COALESCED.
//      blocks 512..895: build WcT[k][c] (transposed combined x_proj/dt weight).
__global__ __launch_bounds__(256) void k2_fused(const float* zseq, const float* aux, const float* auxW,
                                                const float* auxb, const float* rmsw, const float* WTi,
                                                const float* xprojW, const float* dtW,
                                                float* z, float* xsr, float* zg, float* WcT){
  if (blockIdx.x >= 512){
    int r = blockIdx.x - 512; int k = threadIdx.x;
    float v;
    if (r < 256){
      v = 0.f;
      #pragma unroll
      for (int j=0;j<8;j++) v += dtW[r*8+j] * xprojW[j*256+k];
    } else {
      v = xprojW[(8 + r-256)*256 + k];
    }
    WcT[k*384 + r] = v;      // transposed store (uncoalesced but one-off)
    return;
  }
  __shared__ float at[128][8];
  int bt0 = blockIdx.x*8; int tid = threadIdx.x;
  {
    int r = tid>>5, l = tid&31;
    int bt = bt0 + r;
    float a0 = aux[bt*3+0], a1 = aux[bt*3+1], a2 = aux[bt*3+2];
    float zv[4]; float ssq = 0.f;
    #pragma unroll
    for (int j=0;j<4;j++){
      int d = l + 32*j;
      float v = zseq[bt*DM+d] + a0*auxW[d*3+0] + a1*auxW[d*3+1] + a2*auxW[d*3+2] + auxb[d];
      zv[j] = v; ssq += v*v;
    }
    #pragma unroll
    for (int m=16;m>=1;m>>=1) ssq += __shfl_xor(ssq, m);
    float rinv = rsqrtf(ssq*(1.f/DM) + 1e-5f);
    #pragma unroll
    for (int j=0;j<4;j++){
      int d = l + 32*j;
      z[bt*DM+d] = zv[j];
      at[d][r] = zv[j]*rinv*rmsw[d];
    }
  }
  __syncthreads();
  float acc0[8], acc1[8];
  #pragma unroll
  for (int r=0;r<8;r++){ acc0[r]=0.f; acc1[r]=0.f; }
  int c0 = tid;
  for (int k=0;k<128;k++){
    float w0 = WTi[k*512 + c0];          // coalesced: lanes -> consecutive floats
    float w1 = WTi[k*512 + c0 + 256];
    float a[8];
    *(float4*)&a[0] = *(const float4*)&at[k][0];   // broadcast b128 (conflict-free)
    *(float4*)&a[4] = *(const float4*)&at[k][4];
    #pragma unroll
    for (int r=0;r<8;r++){ acc0[r] = fmaf(a[r], w0, acc0[r]); acc1[r] = fmaf(a[r], w1, acc1[r]); }
  }
  #pragma unroll
  for (int r=0;r<8;r++){
    int bt = bt0+r;
    xsr[bt*ED_ + c0] = acc0[r];
    zg [bt*ED_ + c0] = acc1[r];
  }
}

// K4b: conv(k=4)+bias+SiLU from xsr (LDS), then [delta_pre | B | C] = xs @ WcT.
// Weight reads COALESCED (WcT[k][c], c=tid).
__global__ __launch_bounds__(384) void k4b_xproj(const float* xsr, const float* convW, const float* convb,
                                                 const float* WcT, const float* dtb,
                                                 float* dxp, float* bcf){
  __shared__ float at[256][8];
  int bt0 = blockIdx.x*8; int tid = threadIdx.x;
  for (int i=tid;i<2048;i+=384){
    int r=i>>8,k=i&255; int bt=bt0+r; int t = bt & (T_SEQ-1);
    float4 wv = *(const float4*)(convW + k*4);
    float s = convb[k];
    if (t>=3) s += xsr[(bt-3)*ED_+k]*wv.x;
    if (t>=2) s += xsr[(bt-2)*ED_+k]*wv.y;
    if (t>=1) s += xsr[(bt-1)*ED_+k]*wv.z;
    s += xsr[bt*ED_+k]*wv.w;
    at[k][r] = s * sigmoidf_(s);
  }
  __syncthreads();
  float acc[8];
  #pragma unroll
  for (int r=0;r<8;r++) acc[r]=0.f;
  int c = tid;
  for (int k=0;k<256;k++){
    float w = WcT[k*384 + c];            // coalesced
    float a[8];
    *(float4*)&a[0] = *(const float4*)&at[k][0];   // broadcast
    *(float4*)&a[4] = *(const float4*)&at[k][4];
    #pragma unroll
    for (int r=0;r<8;r++) acc[r] = fmaf(a[r], w, acc[r]);
  }
  int b4 = bt0 >> 10, tb = bt0 & (T_SEQ-1);
  if (c < 256){
    float bcv = dtb[c];
    float2* pout = (float2*)dxp + (size_t)(b4*ED_ + c)*T_SEQ + tb;
    #pragma unroll
    for (int r=0;r<8;r++){
      float xv = acc[r] + bcv;
      float dv = (xv > 20.f) ? xv : log1pf(__expf(xv));
      pout[r] = make_float2(dv, dv * at[c][r]);   // {delta, delta*xs}
    }
  } else if (c < 320){
    #pragma unroll
    for (int r=0;r<8;r++) bcf[((size_t)(bt0+r)*NS + (c-256))*2 + 0] = acc[r];
  } else {
    #pragma unroll
    for (int r=0;r<8;r++) bcf[((size_t)(bt0+r)*NS + (c-320))*2 + 1] = acc[r];
  }
}

// K5: bc-amortized chunked scan, OCCUPANCY-DOUBLED vs R13.
// R13 PMC: 45us, VALUBusy 50%, Occupancy 17% (72KB LDS, grid 256 -> 1 block/CU
// = 2 waves/SIMD) -> latency-bound again. Bank conflicts 2.1M are structural
// b64 (read mapping already at the 4-lane/pair minimum) -- not the lever.
// NEW: block = (b, 2 e's), 8 waves x 8 chunks of 128 t; each wave scans ONE
// chunk for BOTH e's (one bc float2 load feeds 2 e's -- amortization kept).
// Grid 512 scan blocks = 2 blocks/CU = 4 waves/SIMD. LDS 74.8KB fits x2.
// Phase-1 redundancy DROPS (7x128=896 t-units vs R13's 6x256=1536).
// launch_bounds(512,4) -> VGPR cap 128 >> demand ~55 (no R2 collapse).
__global__ __launch_bounds__(512,4) void k5_scan(const float* dxpf, const float* bcf,
                                                  const float* Alog, float* yrT,
                                                  const float* outW, float* wot){
  if (blockIdx.x >= 512){
    int bb2 = blockIdx.x - 512;           // 0..15
    int k  = bb2*16 + (threadIdx.x>>5);   // 0..255
    int d  = (threadIdx.x&31)*4;          // 0..124
    float4 v;
    v.x = outW[(d+0)*256 + k];
    v.y = outW[(d+1)*256 + k];
    v.z = outW[(d+2)*256 + k];
    v.w = outW[(d+3)*256 + k];
    *(float4*)&wot[k*128 + d] = v;
    return;
  }
  __shared__ float lcar[7][2][64], lapr[7][2][64];
  __shared__ float red[8][16][2][66];
  int i  = blockIdx.x;
  int tid = threadIdx.x;
  int wv = tid >> 6;             // wave 0..7 == chunk index
  int n  = tid & 63;             // state index (lane)
  int x = i & 7;                 // XCD
  int r = i >> 3;                // 0..63
  int b = r & 3;
  int g = r >> 2;                // 0..15
  int eA = x*32 + g*2;
  int eB = eA + 1;
  const int CH = T_SEQ/8;        // 128
  int t0 = wv*CH;
  float A2A = -__expf(Alog[eA*NS+n]) * LOG2E;
  float A2B = -__expf(Alog[eB*NS+n]) * LOG2E;
  const float2* pdA = (const float2*)dxpf + (size_t)(b*ED_ + eA)*T_SEQ + t0;  // lane=t
  const float2* pdB = (const float2*)dxpf + (size_t)(b*ED_ + eB)*T_SEQ + t0;
  const float2* pbc = (const float2*)bcf  + (size_t)(b*T_SEQ + t0)*NS + n;    // lane=n
  float* pyA = yrT + (size_t)(b*ED_ + eA)*T_SEQ + t0;
  float* pyB = yrT + (size_t)(b*ED_ + eB)*T_SEQ + t0;

  // ---- phase 1: carry-only scan (waves 0..6; wave 7's carry unused)
  if (wv < 7){
    float hA=0.f, hB=0.f, SsA=0.f, SsB=0.f;
    float2 dxcA = pdA[n], dxcB = pdB[n];
    for (int sb=0; sb<CH; sb+=64){
      float2 dxnA = dxcA, dxnB = dxcB;
      if (sb+64 < CH){ dxnA = pdA[sb+64+n]; dxnB = pdB[sb+64+n]; }
      float svA = dxcA.x; DPP6(svA); SsA += rlane_(svA, 63);
      float svB = dxcB.x; DPP6(svB); SsB += rlane_(svB, 63);
      float bA[8], bBv[8];
      #pragma unroll
      for (int j=0;j<8;j++) bA[j] = pbc[(sb+j)*NS].x;
      #pragma unroll
      for (int bb=0; bb<64; bb+=16){
        #pragma unroll
        for (int j=0;j<8;j++) bBv[j] = pbc[(sb+bb+8+j)*NS].x;
        #pragma unroll
        for (int j=0;j<8;j++){
          float sdA = rlane_(dxcA.x, bb+j), suA = rlane_(dxcA.y, bb+j);
          hA = fmaf(exp2_(sdA*A2A), hA, suA*bA[j]);
          float sdB = rlane_(dxcB.x, bb+j), suB = rlane_(dxcB.y, bb+j);
          hB = fmaf(exp2_(sdB*A2B), hB, suB*bA[j]);
        }
        if (bb+16 < 64){
          #pragma unroll
          for (int j=0;j<8;j++) bA[j] = pbc[(sb+bb+16+j)*NS].x;
        }
        #pragma unroll
        for (int j=0;j<8;j++){
          float sdA = rlane_(dxcA.x, bb+8+j), suA = rlane_(dxcA.y, bb+8+j);
          hA = fmaf(exp2_(sdA*A2A), hA, suA*bBv[j]);
          float sdB = rlane_(dxcB.x, bb+8+j), suB = rlane_(dxcB.y, bb+8+j);
          hB = fmaf(exp2_(sdB*A2B), hB, suB*bBv[j]);
        }
      }
      dxcA = dxnA; dxcB = dxnB;
    }
    lcar[wv][0][n] = hA;  lapr[wv][0][n] = exp2_(A2A*SsA);
    lcar[wv][1][n] = hB;  lapr[wv][1][n] = exp2_(A2B*SsB);
  }
  __syncthreads();

  // ---- combine: h_in for this wave's chunk (both e's)
  float hA = 0.f, hB = 0.f;
  #pragma unroll
  for (int q=0;q<7;q++) if (wv > q){
    hA = fmaf(lapr[q][0][n], hA, lcar[q][0][n]);
    hB = fmaf(lapr[q][1][n], hB, lcar[q][1][n]);
  }

  // ---- phase 2: full output scan, shared bc load feeds both e's
  {
    float2 dxcA = pdA[n], dxcB = pdB[n];
    int ri = n & 31, hs = n >> 5;
    int eh = ri >> 4, tr = ri & 15;
    const float2* rp = (const float2*)&red[wv][tr][eh][hs*32];
    float* pyE = eh ? pyB : pyA;
    for (int sb=0; sb<CH; sb+=64){
      float2 dxnA = dxcA, dxnB = dxcB;
      if (sb+64 < CH){ dxnA = pdA[sb+64+n]; dxnB = pdB[sb+64+n]; }
      float2 cA[8], cB[8];
      #pragma unroll
      for (int j=0;j<8;j++) cA[j] = pbc[(sb+j)*NS];
      #pragma unroll
      for (int bb=0; bb<64; bb+=16){
        #pragma unroll
        for (int j=0;j<8;j++) cB[j] = pbc[(sb+bb+8+j)*NS];
        #pragma unroll
        for (int j=0;j<8;j++){
          float sdA = rlane_(dxcA.x, bb+j), suA = rlane_(dxcA.y, bb+j);
          hA = fmaf(exp2_(sdA*A2A), hA, suA*cA[j].x);
          red[wv][j][0][n] = hA*cA[j].y;
          float sdB = rlane_(dxcB.x, bb+j), suB = rlane_(dxcB.y, bb+j);
          hB = fmaf(exp2_(sdB*A2B), hB, suB*cA[j].x);
          red[wv][j][1][n] = hB*cA[j].y;
        }
        if (bb+16 < 64){
          #pragma unroll
          for (int j=0;j<8;j++) cA[j] = pbc[(sb+bb+16+j)*NS];
        }
        #pragma unroll
        for (int j=0;j<8;j++){
          float sdA = rlane_(dxcA.x, bb+8+j), suA = rlane_(dxcA.y, bb+8+j);
          hA = fmaf(exp2_(sdA*A2A), hA, suA*cB[j].x);
          red[wv][8+j][0][n] = hA*cB[j].y;
          float sdB = rlane_(dxcB.x, bb+8+j), suB = rlane_(dxcB.y, bb+8+j);
          hB = fmaf(exp2_(sdB*A2B), hB, suB*cB[j].x);
          red[wv][8+j][1][n] = hB*cB[j].y;
        }
        // transpose-reduce the 16t x 2e tile (same-wave DS ops are in-order)
        float s = 0.f;
        #pragma unroll
        for (int jj=0;jj<16;jj++){ float2 v = rp[jj]; s += v.x + v.y; }
        s += __shfl_xor(s, 32);
        if (n < 32) pyE[sb + bb + tr] = s;
      }
      dxcA = dxnA; dxcB = dxnB;
    }
  }
}

// K6: stage yrT (e-major) + xs = u/delta from dxpT via LDS; combine with gate;
// then out = LayerNorm(y @ out_proj_W.T + 2*z)*ln_w + ln_b. WoT reads coalesced.
__global__ __launch_bounds__(256) void k6_out(const float* yrT, const float* dxpf, const float* zg,
                                               const float* Dp, const float* wot, const float* z,
                                               const float* lnw, const float* lnb, float* out){
  __shared__ float yt[256][8];
  __shared__ float xst[256][8];
  __shared__ float psum[4][4], psq[4][4];
  int bt0 = blockIdx.x*8; int tid = threadIdx.x;
  int b4 = bt0 >> 10, tb = bt0 & (T_SEQ-1);
  int el = tid>>3, tl = tid&7;
  #pragma unroll
  for (int gg=0; gg<8; gg++){
    int ee = el + gg*32;
    size_t base = (size_t)(b4*ED_ + ee)*T_SEQ + tb + tl;
    float2 du = ((const float2*)dxpf)[base];
    yt[ee][tl]  = yrT[base];
    xst[ee][tl] = du.y / du.x;        // xs = (delta*xs)/delta; delta >= softplus(-4) ~ 0.018
  }
  __syncthreads();
  for (int i=tid;i<2048;i+=256){
    int rr=i>>8, k=i&255; int bt=bt0+rr;
    float zgv = zg[bt*ED_ + k];
    float yv  = yt[k][rr] + Dp[k]*xst[k][rr];
    yt[k][rr] = yv * zgv * sigmoidf_(zgv);
  }
  __syncthreads();
  int d = tid & 127, gdx = tid>>7;
  float acc[4] = {0.f,0.f,0.f,0.f};
  for (int k=0;k<256;k+=4){
    float w0 = wot[(k+0)*128 + d];       // coalesced
    float w1 = wot[(k+1)*128 + d];
    float w2 = wot[(k+2)*128 + d];
    float w3 = wot[(k+3)*128 + d];
    float4 q0 = *(const float4*)&yt[k+0][gdx*4];   // broadcast
    float4 q1 = *(const float4*)&yt[k+1][gdx*4];
    float4 q2 = *(const float4*)&yt[k+2][gdx*4];
    float4 q3 = *(const float4*)&yt[k+3][gdx*4];
    acc[0] = fmaf(q0.x,w0,acc[0]); acc[1] = fmaf(q0.y,w0,acc[1]);
    acc[2] = fmaf(q0.z,w0,acc[2]); acc[3] = fmaf(q0.w,w0,acc[3]);
    acc[0] = fmaf(q1.x,w1,acc[0]); acc[1] = fmaf(q1.y,w1,acc[1]);
    acc[2] = fmaf(q1.z,w1,acc[2]); acc[3] = fmaf(q1.w,w1,acc[3]);
    acc[0] = fmaf(q2.x,w2,acc[0]); acc[1] = fmaf(q2.y,w2,acc[1]);
    acc[2] = fmaf(q2.z,w2,acc[2]); acc[3] = fmaf(q2.w,w2,acc[3]);
    acc[0] = fmaf(q3.x,w3,acc[0]); acc[1] = fmaf(q3.y,w3,acc[1]);
    acc[2] = fmaf(q3.z,w3,acc[2]); acc[3] = fmaf(q3.w,w3,acc[3]);
  }
  float val[4];
  #pragma unroll
  for (int j=0;j<4;j++){
    int bt = bt0 + gdx*4 + j;
    val[j] = acc[j] + 2.f*z[bt*DM + d];
  }
  int w_id = tid>>6;
  #pragma unroll
  for (int j=0;j<4;j++){
    float s = val[j], q = val[j]*val[j];
    #pragma unroll
    for (int off=32; off>=1; off>>=1){ s += __shfl_down(s, off); q += __shfl_down(q, off); }
    if ((tid&63)==0){ psum[w_id][j]=s; psq[w_id][j]=q; }
  }
  __syncthreads();
  float lw = lnw[d], lb = lnb[d];
  #pragma unroll
  for (int j=0;j<4;j++){
    int bt = bt0 + gdx*4 + j;
    float sum = psum[gdx*2][j] + psum[gdx*2+1][j];
    float sq  = psq [gdx*2][j] + psq [gdx*2+1][j];
    float mu  = sum*(1.f/DM);
    float var = sq*(1.f/DM) - mu*mu;
    float inv = rsqrtf(var + 1e-5f);
    out[bt*DM + d] = (val[j]-mu)*inv*lw + lb;
  }
}

extern "C" void kernel_launch(void* const* d_in, const int* in_sizes, int n_in,
                              void* d_out, int out_size, void* d_ws, size_t ws_size,
                              hipStream_t stream){
  const float* zseq = (const float*)d_in[0];
  const float* aux  = (const float*)d_in[1];
  const float* auxW = (const float*)d_in[2];
  const float* auxb = (const float*)d_in[3];
  const float* lnw  = (const float*)d_in[4];
  const float* lnb  = (const float*)d_in[5];
  const float* rmsw = (const float*)d_in[6];
  const float* inW  = (const float*)d_in[7];
  const float* convW= (const float*)d_in[8];
  const float* convb= (const float*)d_in[9];
  const float* xpW  = (const float*)d_in[10];
  const float* dtW  = (const float*)d_in[11];
  const float* dtb  = (const float*)d_in[12];
  const float* Alog = (const float*)d_in[13];
  const float* Dp   = (const float*)d_in[14];
  const float* outW = (const float*)d_in[15];
  float* out = (float*)d_out;
  float* ws = (float*)d_ws;

  float* z   = ws+OFF_Z;
  float* zg  = ws+OFF_ZG;
  float* xsr = ws+OFF_XSR;
  float* wot = ws+OFF_XSR;   // WoT hosted in XSR head; xsr dead after k4b
  float* WcT = ws+OFF_WC;
  float* yr  = ws+OFF_YR;
  float* wti = ws+OFF_YR;    // WTi hosted in YR head; dead before k5 writes yr
  float* dxp = ws+OFF_DPX;
  float* bcp = ws+OFF_BC;

  k0_t     <<<128,256,0,stream>>>(inW, wti);
  k2_fused <<<896,256,0,stream>>>(zseq,aux,auxW,auxb,rmsw,wti,xpW,dtW,z,xsr,zg,WcT);
  k4b_xproj<<<512,384,0,stream>>>(xsr,convW,convb,WcT,dtb,dxp,bcp);
  k5_scan  <<<528,512,0,stream>>>(dxp,bcp,Alog,yr,outW,wot);
  k6_out   <<<512,256,0,stream>>>(yr,dxp,zg,Dp,wot,z,lnw,lnb,out);
}

// Round 15
// 178.464 us; speedup vs baseline: 1.0512x; 1.0512x over previous
//
#include <hip/hip_runtime.h>
#include <hip/hip_bf16.h>

#define B_SZ 4
#define T_SEQ 1024
#define DM 128
#define ED_ 256
#define NS 64
#define LOG2E 1.44269504088896340736f

// workspace layout (float elements). Total = 6,389,760 floats = 25.6 MB (accepted size).
// dxpT is TRANSPOSED [b][e][t] x {delta, delta*xs}; yrT is TRANSPOSED [b][e][t].
// WTiv (in_proj, float4-over-k x c) lives in the YR head: k0 -> k2, dead before k5 writes YR.
// wotv (out_proj, float4-over-k x d) lives in the XSR head: k5 extra blocks -> k6.
// R15 theory: R9's coalesced-but-SCALAR-k weight loads quadrupled VMEM instrs
// vs R1's k-vectorized loads. New layouts are coalesced AND k-vectorized:
// float4 spans k=4k4..4k4+3, lanes run over columns -> 16B/lane, 4 k's/load.
#define OFF_Z      0u         /* 524288  f32  z (residual, read by K6)            */
#define OFF_ZG     524288u    /* 1048576 f32  gate (k2 -> k6)                     */
#define OFF_XSR    1572864u   /* 1048576 f32  conv input (k2 -> k4b); head=wotv   */
#define OFF_WC     2621440u   /* 98304   f32  Wcv[k4][c] float4-over-k weight     */
#define OFF_YR     2719744u   /* 1048576 f32  scan out [b][e][t]; head hosts WTiv */
#define OFF_DPX    3768320u   /* 2097152 f32  {delta, delta*xs} [b][e][t] pairs   */
#define OFF_BC     5865472u   /* 524288  f32  {B, C} [b][t][n] pairs (k4b -> k5)  */

__device__ __forceinline__ float sigmoidf_(float x){ return 1.f/(1.f+__expf(-x)); }
__device__ __forceinline__ float exp2_(float x){ return __builtin_amdgcn_exp2f(x); }
__device__ __forceinline__ float rlane_(float v, int l){
  return __int_as_float(__builtin_amdgcn_readlane(__float_as_int(v), l));
}

// Fused DPP add: p += dpp(p) in ONE instruction. bound_ctrl:0 => invalid lanes read 0.
#define DPPR(p, ctl) asm("v_add_f32_dpp %0, %0, %0 " ctl " row_mask:0xf bank_mask:0xf bound_ctrl:0" : "+v"(p))
#define DPP6(p) do{ DPPR(p,"row_shr:1"); DPPR(p,"row_shr:2"); DPPR(p,"row_shr:4"); \
                    DPPR(p,"row_shr:8"); DPPR(p,"row_bcast:15"); DPPR(p,"row_bcast:31"); }while(0)

// K0: build WTiv: float4[(k4*512)+c] = {W[c][4k4+0..3]} (in_proj is [512][128] row-major,
// k contiguous -> aligned float4 read). Write coalesced 16B/lane.
__global__ __launch_bounds__(256) void k0_t(const float* W, float* WTi){
  int k4 = blockIdx.x >> 1;               // 0..31
  int c  = (blockIdx.x & 1)*256 + threadIdx.x;
  float4 w = *(const float4*)&W[(size_t)c*128 + 4*k4];
  ((float4*)WTi)[k4*512 + c] = w;
}

// K2f: blocks 0..511: fused [z = zseq+aux@auxW.T+auxb ; zn=RMSNorm(z)*rms_w] -> LDS,
//      then xz = zn @ in_proj_W.T -> xsr | zg via WTiv (coalesced + 4k/load).
//      blocks 512..895: build Wcv[k4][c] (combined x_proj/dt weight, float4-over-k).
__global__ __launch_bounds__(256) void k2_fused(const float* zseq, const float* aux, const float* auxW,
                                                const float* auxb, const float* rmsw, const float* WTi,
                                                const float* xprojW, const float* dtW,
                                                float* z, float* xsr, float* zg, float* WcT){
  if (blockIdx.x >= 512){
    int r = blockIdx.x - 512; int k = threadIdx.x;
    float v;
    if (r < 256){
      v = 0.f;
      #pragma unroll
      for (int j=0;j<8;j++) v += dtW[r*8+j] * xprojW[j*256+k];
    } else {
      v = xprojW[(8 + r-256)*256 + k];
    }
    WcT[((k>>2)*384 + r)*4 + (k&3)] = v;   // scalar store into float4-over-k slot (one-off)
    return;
  }
  __shared__ float at[128][8];
  int bt0 = blockIdx.x*8; int tid = threadIdx.x;
  {
    int r = tid>>5, l = tid&31;
    int bt = bt0 + r;
    float a0 = aux[bt*3+0], a1 = aux[bt*3+1], a2 = aux[bt*3+2];
    float zv[4]; float ssq = 0.f;
    #pragma unroll
    for (int j=0;j<4;j++){
      int d = l + 32*j;
      float v = zseq[bt*DM+d] + a0*auxW[d*3+0] + a1*auxW[d*3+1] + a2*auxW[d*3+2] + auxb[d];
      zv[j] = v; ssq += v*v;
    }
    #pragma unroll
    for (int m=16;m>=1;m>>=1) ssq += __shfl_xor(ssq, m);
    float rinv = rsqrtf(ssq*(1.f/DM) + 1e-5f);
    #pragma unroll
    for (int j=0;j<4;j++){
      int d = l + 32*j;
      z[bt*DM+d] = zv[j];
      at[d][r] = zv[j]*rinv*rmsw[d];
    }
  }
  __syncthreads();
  float acc0[8], acc1[8];
  #pragma unroll
  for (int r=0;r<8;r++){ acc0[r]=0.f; acc1[r]=0.f; }
  int c0 = tid;
  const float4* WTv = (const float4*)WTi;
  for (int k4=0;k4<32;k4++){
    float4 w0 = WTv[k4*512 + c0];        // coalesced 16B/lane, 4 k's
    float4 w1 = WTv[k4*512 + c0 + 256];
    float w0a[4] = {w0.x,w0.y,w0.z,w0.w};
    float w1a[4] = {w1.x,w1.y,w1.z,w1.w};
    #pragma unroll
    for (int kk=0;kk<4;kk++){
      float a[8];
      *(float4*)&a[0] = *(const float4*)&at[4*k4+kk][0];   // broadcast b128
      *(float4*)&a[4] = *(const float4*)&at[4*k4+kk][4];
      #pragma unroll
      for (int r=0;r<8;r++){ acc0[r] = fmaf(a[r], w0a[kk], acc0[r]); acc1[r] = fmaf(a[r], w1a[kk], acc1[r]); }
    }
  }
  #pragma unroll
  for (int r=0;r<8;r++){
    int bt = bt0+r;
    xsr[bt*ED_ + c0] = acc0[r];
    zg [bt*ED_ + c0] = acc1[r];
  }
}

// K4b: conv(k=4)+bias+SiLU from xsr (LDS), then [delta_pre | B | C] = xs @ Wc
// via Wcv (coalesced + 4k/load).
__global__ __launch_bounds__(384) void k4b_xproj(const float* xsr, const float* convW, const float* convb,
                                                 const float* WcT, const float* dtb,
                                                 float* dxp, float* bcf){
  __shared__ float at[256][8];
  int bt0 = blockIdx.x*8; int tid = threadIdx.x;
  for (int i=tid;i<2048;i+=384){
    int r=i>>8,k=i&255; int bt=bt0+r; int t = bt & (T_SEQ-1);
    float4 wv = *(const float4*)(convW + k*4);
    float s = convb[k];
    if (t>=3) s += xsr[(bt-3)*ED_+k]*wv.x;
    if (t>=2) s += xsr[(bt-2)*ED_+k]*wv.y;
    if (t>=1) s += xsr[(bt-1)*ED_+k]*wv.z;
    s += xsr[bt*ED_+k]*wv.w;
    at[k][r] = s * sigmoidf_(s);
  }
  __syncthreads();
  float acc[8];
  #pragma unroll
  for (int r=0;r<8;r++) acc[r]=0.f;
  int c = tid;
  const float4* Wv = (const float4*)WcT;
  for (int k4=0;k4<64;k4++){
    float4 w = Wv[k4*384 + c];           // coalesced 16B/lane, 4 k's
    float wa[4] = {w.x,w.y,w.z,w.w};
    #pragma unroll
    for (int kk=0;kk<4;kk++){
      float a[8];
      *(float4*)&a[0] = *(const float4*)&at[4*k4+kk][0];   // broadcast
      *(float4*)&a[4] = *(const float4*)&at[4*k4+kk][4];
      #pragma unroll
      for (int r=0;r<8;r++) acc[r] = fmaf(a[r], wa[kk], acc[r]);
    }
  }
  int b4 = bt0 >> 10, tb = bt0 & (T_SEQ-1);
  if (c < 256){
    float bcv = dtb[c];
    float2* pout = (float2*)dxp + (size_t)(b4*ED_ + c)*T_SEQ + tb;
    #pragma unroll
    for (int r=0;r<8;r++){
      float xv = acc[r] + bcv;
      float dv = (xv > 20.f) ? xv : log1pf(__expf(xv));
      pout[r] = make_float2(dv, dv * at[c][r]);   // {delta, delta*xs}
    }
  } else if (c < 320){
    #pragma unroll
    for (int r=0;r<8;r++) bcf[((size_t)(bt0+r)*NS + (c-256))*2 + 0] = acc[r];
  } else {
    #pragma unroll
    for (int r=0;r<8;r++) bcf[((size_t)(bt0+r)*NS + (c-320))*2 + 1] = acc[r];
  }
}

// K5: bc-amortized chunked scan (R14 config, measured 43.6us): block = (b, 2 e's),
// 8 waves x 8 chunks of 128 t; one bc float2 load feeds 2 e's. Grid 512 scan
// blocks + 16 wotv-builder blocks. launch_bounds(512,4).
__global__ __launch_bounds__(512,4) void k5_scan(const float* dxpf, const float* bcf,
                                                  const float* Alog, float* yrT,
                                                  const float* outW, float* wot){
  if (blockIdx.x >= 512){
    int idx = (blockIdx.x - 512)*512 + threadIdx.x;   // 0..8191
    int k4 = idx >> 7;                                // 0..63
    int d  = idx & 127;
    float4 v = *(const float4*)&outW[(size_t)d*256 + 4*k4];  // 4 k's, aligned
    ((float4*)wot)[k4*128 + d] = v;                   // coalesced over d
    return;
  }
  __shared__ float lcar[7][2][64], lapr[7][2][64];
  __shared__ float red[8][16][2][66];
  int i  = blockIdx.x;
  int tid = threadIdx.x;
  int wv = tid >> 6;             // wave 0..7 == chunk index
  int n  = tid & 63;             // state index (lane)
  int x = i & 7;                 // XCD
  int r = i >> 3;                // 0..63
  int b = r & 3;
  int g = r >> 2;                // 0..15
  int eA = x*32 + g*2;
  int eB = eA + 1;
  const int CH = T_SEQ/8;        // 128
  int t0 = wv*CH;
  float A2A = -__expf(Alog[eA*NS+n]) * LOG2E;
  float A2B = -__expf(Alog[eB*NS+n]) * LOG2E;
  const float2* pdA = (const float2*)dxpf + (size_t)(b*ED_ + eA)*T_SEQ + t0;  // lane=t
  const float2* pdB = (const float2*)dxpf + (size_t)(b*ED_ + eB)*T_SEQ + t0;
  const float2* pbc = (const float2*)bcf  + (size_t)(b*T_SEQ + t0)*NS + n;    // lane=n
  float* pyA = yrT + (size_t)(b*ED_ + eA)*T_SEQ + t0;
  float* pyB = yrT + (size_t)(b*ED_ + eB)*T_SEQ + t0;

  // ---- phase 1: carry-only scan (waves 0..6; wave 7's carry unused)
  if (wv < 7){
    float hA=0.f, hB=0.f, SsA=0.f, SsB=0.f;
    float2 dxcA = pdA[n], dxcB = pdB[n];
    for (int sb=0; sb<CH; sb+=64){
      float2 dxnA = dxcA, dxnB = dxcB;
      if (sb+64 < CH){ dxnA = pdA[sb+64+n]; dxnB = pdB[sb+64+n]; }
      float svA = dxcA.x; DPP6(svA); SsA += rlane_(svA, 63);
      float svB = dxcB.x; DPP6(svB); SsB += rlane_(svB, 63);
      float bA[8], bBv[8];
      #pragma unroll
      for (int j=0;j<8;j++) bA[j] = pbc[(sb+j)*NS].x;
      #pragma unroll
      for (int bb=0; bb<64; bb+=16){
        #pragma unroll
        for (int j=0;j<8;j++) bBv[j] = pbc[(sb+bb+8+j)*NS].x;
        #pragma unroll
        for (int j=0;j<8;j++){
          float sdA = rlane_(dxcA.x, bb+j), suA = rlane_(dxcA.y, bb+j);
          hA = fmaf(exp2_(sdA*A2A), hA, suA*bA[j]);
          float sdB = rlane_(dxcB.x, bb+j), suB = rlane_(dxcB.y, bb+j);
          hB = fmaf(exp2_(sdB*A2B), hB, suB*bA[j]);
        }
        if (bb+16 < 64){
          #pragma unroll
          for (int j=0;j<8;j++) bA[j] = pbc[(sb+bb+16+j)*NS].x;
        }
        #pragma unroll
        for (int j=0;j<8;j++){
          float sdA = rlane_(dxcA.x, bb+8+j), suA = rlane_(dxcA.y, bb+8+j);
          hA = fmaf(exp2_(sdA*A2A), hA, suA*bBv[j]);
          float sdB = rlane_(dxcB.x, bb+8+j), suB = rlane_(dxcB.y, bb+8+j);
          hB = fmaf(exp2_(sdB*A2B), hB, suB*bBv[j]);
        }
      }
      dxcA = dxnA; dxcB = dxnB;
    }
    lcar[wv][0][n] = hA;  lapr[wv][0][n] = exp2_(A2A*SsA);
    lcar[wv][1][n] = hB;  lapr[wv][1][n] = exp2_(A2B*SsB);
  }
  __syncthreads();

  // ---- combine: h_in for this wave's chunk (both e's)
  float hA = 0.f, hB = 0.f;
  #pragma unroll
  for (int q=0;q<7;q++) if (wv > q){
    hA = fmaf(lapr[q][0][n], hA, lcar[q][0][n]);
    hB = fmaf(lapr[q][1][n], hB, lcar[q][1][n]);
  }

  // ---- phase 2: full output scan, shared bc load feeds both e's
  {
    float2 dxcA = pdA[n], dxcB = pdB[n];
    int ri = n & 31, hs = n >> 5;
    int eh = ri >> 4, tr = ri & 15;
    const float2* rp = (const float2*)&red[wv][tr][eh][hs*32];
    float* pyE = eh ? pyB : pyA;
    for (int sb=0; sb<CH; sb+=64){
      float2 dxnA = dxcA, dxnB = dxcB;
      if (sb+64 < CH){ dxnA = pdA[sb+64+n]; dxnB = pdB[sb+64+n]; }
      float2 cA[8], cB[8];
      #pragma unroll
      for (int j=0;j<8;j++) cA[j] = pbc[(sb+j)*NS];
      #pragma unroll
      for (int bb=0; bb<64; bb+=16){
        #pragma unroll
        for (int j=0;j<8;j++) cB[j] = pbc[(sb+bb+8+j)*NS];
        #pragma unroll
        for (int j=0;j<8;j++){
          float sdA = rlane_(dxcA.x, bb+j), suA = rlane_(dxcA.y, bb+j);
          hA = fmaf(exp2_(sdA*A2A), hA, suA*cA[j].x);
          red[wv][j][0][n] = hA*cA[j].y;
          float sdB = rlane_(dxcB.x, bb+j), suB = rlane_(dxcB.y, bb+j);
          hB = fmaf(exp2_(sdB*A2B), hB, suB*cA[j].x);
          red[wv][j][1][n] = hB*cA[j].y;
        }
        if (bb+16 < 64){
          #pragma unroll
          for (int j=0;j<8;j++) cA[j] = pbc[(sb+bb+16+j)*NS];
        }
        #pragma unroll
        for (int j=0;j<8;j++){
          float sdA = rlane_(dxcA.x, bb+8+j), suA = rlane_(dxcA.y, bb+8+j);
          hA = fmaf(exp2_(sdA*A2A), hA, suA*cB[j].x);
          red[wv][8+j][0][n] = hA*cB[j].y;
          float sdB = rlane_(dxcB.x, bb+8+j), suB = rlane_(dxcB.y, bb+8+j);
          hB = fmaf(exp2_(sdB*A2B), hB, suB*cB[j].x);
          red[wv][8+j][1][n] = hB*cB[j].y;
        }
        // transpose-reduce the 16t x 2e tile (same-wave DS ops are in-order)
        float s = 0.f;
        #pragma unroll
        for (int jj=0;jj<16;jj++){ float2 v = rp[jj]; s += v.x + v.y; }
        s += __shfl_xor(s, 32);
        if (n < 32) pyE[sb + bb + tr] = s;
      }
      dxcA = dxnA; dxcB = dxnB;
    }
  }
}

// K6: stage yrT (e-major) + xs = u/delta from dxpT via LDS; combine with gate;
// then out = LayerNorm(y @ out_proj_W.T + 2*z)*ln_w + ln_b.
// Weight reads via wotv: coalesced over d AND 4 k's per float4 load.
__global__ __launch_bounds__(256) void k6_out(const float* yrT, const float* dxpf, const float* zg,
                                               const float* Dp, const float* wot, const float* z,
                                               const float* lnw, const float* lnb, float* out){
  __shared__ float yt[256][8];
  __shared__ float xst[256][8];
  __shared__ float psum[4][4], psq[4][4];
  int bt0 = blockIdx.x*8; int tid = threadIdx.x;
  int b4 = bt0 >> 10, tb = bt0 & (T_SEQ-1);
  int el = tid>>3, tl = tid&7;
  #pragma unroll
  for (int gg=0; gg<8; gg++){
    int ee = el + gg*32;
    size_t base = (size_t)(b4*ED_ + ee)*T_SEQ + tb + tl;
    float2 du = ((const float2*)dxpf)[base];
    yt[ee][tl]  = yrT[base];
    xst[ee][tl] = du.y / du.x;        // xs = (delta*xs)/delta; delta >= softplus(-4) ~ 0.018
  }
  __syncthreads();
  for (int i=tid;i<2048;i+=256){
    int rr=i>>8, k=i&255; int bt=bt0+rr;
    float zgv = zg[bt*ED_ + k];
    float yv  = yt[k][rr] + Dp[k]*xst[k][rr];
    yt[k][rr] = yv * zgv * sigmoidf_(zgv);
  }
  __syncthreads();
  int d = tid & 127, gdx = tid>>7;
  float acc[4] = {0.f,0.f,0.f,0.f};
  const float4* Wv = (const float4*)wot;
  for (int k4=0;k4<64;k4++){
    float4 w = Wv[k4*128 + d];           // coalesced 16B/lane, 4 k's
    int k = k4*4;
    float4 q0 = *(const float4*)&yt[k+0][gdx*4];   // broadcast
    float4 q1 = *(const float4*)&yt[k+1][gdx*4];
    float4 q2 = *(const float4*)&yt[k+2][gdx*4];
    float4 q3 = *(const float4*)&yt[k+3][gdx*4];
    acc[0] = fmaf(q0.x,w.x,acc[0]); acc[1] = fmaf(q0.y,w.x,acc[1]);
    acc[2] = fmaf(q0.z,w.x,acc[2]); acc[3] = fmaf(q0.w,w.x,acc[3]);
    acc[0] = fmaf(q1.x,w.y,acc[0]); acc[1] = fmaf(q1.y,w.y,acc[1]);
    acc[2] = fmaf(q1.z,w.y,acc[2]); acc[3] = fmaf(q1.w,w.y,acc[3]);
    acc[0] = fmaf(q2.x,w.z,acc[0]); acc[1] = fmaf(q2.y,w.z,acc[1]);
    acc[2] = fmaf(q2.z,w.z,acc[2]); acc[3] = fmaf(q2.w,w.z,acc[3]);
    acc[0] = fmaf(q3.x,w.w,acc[0]); acc[1] = fmaf(q3.y,w.w,acc[1]);
    acc[2] = fmaf(q3.z,w.w,acc[2]); acc[3] = fmaf(q3.w,w.w,acc[3]);
  }
  float val[4];
  #pragma unroll
  for (int j=0;j<4;j++){
    int bt = bt0 + gdx*4 + j;
    val[j] = acc[j] + 2.f*z[bt*DM + d];
  }
  int w_id = tid>>6;
  #pragma unroll
  for (int j=0;j<4;j++){
    float s = val[j], q = val[j]*val[j];
    #pragma unroll
    for (int off=32; off>=1; off>>=1){ s += __shfl_down(s, off); q += __shfl_down(q, off); }
    if ((tid&63)==0){ psum[w_id][j]=s; psq[w_id][j]=q; }
  }
  __syncthreads();
  float lw = lnw[d], lb = lnb[d];
  #pragma unroll
  for (int j=0;j<4;j++){
    int bt = bt0 + gdx*4 + j;
    float sum = psum[gdx*2][j] + psum[gdx*2+1][j];
    float sq  = psq [gdx*2][j] + psq [gdx*2+1][j];
    float mu  = sum*(1.f/DM);
    float var = sq*(1.f/DM) - mu*mu;
    float inv = rsqrtf(var + 1e-5f);
    out[bt*DM + d] = (val[j]-mu)*inv*lw + lb;
  }
}

extern "C" void kernel_launch(void* const* d_in, const int* in_sizes, int n_in,
                              void* d_out, int out_size, void* d_ws, size_t ws_size,
                              hipStream_t stream){
  const float* zseq = (const float*)d_in[0];
  const float* aux  = (const float*)d_in[1];
  const float* auxW = (const float*)d_in[2];
  const float* auxb = (const float*)d_in[3];
  const float* lnw  = (const float*)d_in[4];
  const float* lnb  = (const float*)d_in[5];
  const float* rmsw = (const float*)d_in[6];
  const float* inW  = (const float*)d_in[7];
  const float* convW= (const float*)d_in[8];
  const float* convb= (const float*)d_in[9];
  const float* xpW  = (const float*)d_in[10];
  const float* dtW  = (const float*)d_in[11];
  const float* dtb  = (const float*)d_in[12];
  const float* Alog = (const float*)d_in[13];
  const float* Dp   = (const float*)d_in[14];
  const float* outW = (const float*)d_in[15];
  float* out = (float*)d_out;
  float* ws = (float*)d_ws;

  float* z   = ws+OFF_Z;
  float* zg  = ws+OFF_ZG;
  float* xsr = ws+OFF_XSR;
  float* wot = ws+OFF_XSR;   // wotv hosted in XSR head; xsr dead after k4b
  float* WcT = ws+OFF_WC;
  float* yr  = ws+OFF_YR;
  float* wti = ws+OFF_YR;    // WTiv hosted in YR head; dead before k5 writes yr
  float* dxp = ws+OFF_DPX;
  float* bcp = ws+OFF_BC;

  k0_t     <<<64,256,0,stream>>>(inW, wti);
  k2_fused <<<896,256,0,stream>>>(zseq,aux,auxW,auxb,rmsw,wti,xpW,dtW,z,xsr,zg,WcT);
  k4b_xproj<<<512,384,0,stream>>>(xsr,convW,convb,WcT,dtb,dxp,bcp);
  k5_scan  <<<528,512,0,stream>>>(dxp,bcp,Alog,yr,outW,wot);
  k6_out   <<<512,256,0,stream>>>(yr,dxp,zg,Dp,wot,z,lnw,lnb,out);
}